// Round 16
// baseline (259.176 us; speedup 1.0000x reference)
//
#include <hip/hip_runtime.h>

// FFF tree-routed feedforward: B=65536, nIn=nOut=1024, DEPTH=10, n_nodes=1023.
//
// Round-16 (single change from R13/R15: route occupancy 1->2 blocks/CU):
//  - route_kernel: LDS stage shrunk to levels 0..3 (15 rows, 60KB) so TWO
//    1024-thread blocks fit per CU (120KB LDS, 32 waves/CU vs 16). R14's
//    counters showed route at 35% occupancy, latency-bound on the dependent
//    deep gather — more waves is the only lever that adds latency hiding
//    without adding per-wave work (R14's 2x-dot mistake) or per-wave
//    registers (R11's prefetch mistake). Level 4 (16 rows, 64KB, hit by all
//    samples) moves to L1/L2 — cache-hot. __launch_bounds__(1024,8) caps
//    VGPR at 64 to allow 2 resident blocks.
//  - accum_kernel: byte-identical to R13 (8 blocks/leaf).
//  - Banked: sc0 sc1 nt streaming stores (R7: kills MALL write-allocate
//    phantom); leaf binning + LDS w2 stage (R5-R7); blocks/leaf 8 (R13).
//    Rejected: 4-sample accum combo (corrupts, R9/R10), x-prefetch (R11),
//    speculation (R14).

#define FFF_DEPTH 10
#define N_IN 1024
#define N_OUT 1024
#define N_LEAF 512
#define LEAF_BASE 511
#define BIN_CAP 512
#define N_STAGE 15            // nodes in levels 0..3 (60KB LDS)
#define ROUTE_THREADS 1024
#define ROUTE_BLOCKS 512      // 2 blocks/CU
#define BLOCKS_PER_LEAF 8

typedef float f32x4 __attribute__((ext_vector_type(4)));

template<int CTRL, int ROW_MASK>
__device__ __forceinline__ float dpp_add(float v) {
    int sh = __builtin_amdgcn_update_dpp(0, __builtin_bit_cast(int, v),
                                         CTRL, ROW_MASK, 0xf, true);
    return v + __builtin_bit_cast(float, sh);
}

// Full 64-lane sum, result broadcast via readlane(63) (wave-uniform).
__device__ __forceinline__ float wave_sum(float p) {
    p = dpp_add<0x111, 0xf>(p);
    p = dpp_add<0x112, 0xf>(p);
    p = dpp_add<0x114, 0xf>(p);
    p = dpp_add<0x118, 0xf>(p);
    p = dpp_add<0x142, 0xa>(p);
    p = dpp_add<0x143, 0xc>(p);
    return __builtin_bit_cast(float,
        __builtin_amdgcn_readlane(__builtin_bit_cast(int, p), 63));
}

// System-scope streaming store: bypasses L2 AND MALL allocate, so the store
// does not trigger a line fetch from HBM (R7-verified: killed ~360MB phantom).
__device__ __forceinline__ void store_stream(f32x4 v, f32x4* addr) {
    asm volatile("global_store_dwordx4 %0, %1, off sc0 sc1 nt"
                 :: "v"(addr), "v"(v) : "memory");
}

// One routing level for both of the wave's samples. Math identical across
// LDS/global sources (same op order) -> bitwise-stable lams.
#define ROUTE_LEVEL_BODY(dd, wa, wb)                                          \
    {                                                                         \
        f32x4 w0[4], w1v[4];                                                  \
        _Pragma("unroll")                                                     \
        for (int c = 0; c < 4; ++c) {                                         \
            w0[c] = (wa)[c * 64 + lane];                                      \
            w1v[c] = (wb)[c * 64 + lane];                                     \
        }                                                                     \
        float p0 = 0.f, p1 = 0.f, p2 = 0.f, p3 = 0.f;                         \
        float q0 = 0.f, q1 = 0.f, q2 = 0.f, q3 = 0.f;                         \
        _Pragma("unroll")                                                     \
        for (int c = 0; c < 4; ++c) {                                         \
            p0 += xv0[c][0] * w0[c][0];  q0 += xv1[c][0] * w1v[c][0];         \
            p1 += xv0[c][1] * w0[c][1];  q1 += xv1[c][1] * w1v[c][1];         \
            p2 += xv0[c][2] * w0[c][2];  q2 += xv1[c][2] * w1v[c][2];         \
            p3 += xv0[c][3] * w0[c][3];  q3 += xv1[c][3] * w1v[c][3];         \
        }                                                                     \
        const float lam0 = wave_sum((p0 + p1) + (p2 + p3));                   \
        const float lam1 = wave_sum((q0 + q1) + (q2 + q3));                   \
        const float pick = (lane < 16) ? lam0 : lam1;                         \
        myl = (sel == (dd)) ? pick : myl;                                     \
        n0 = n0 * 2 + 1 + (lam0 > 0.f ? 1 : 0);                               \
        n1 = n1 * 2 + 1 + (lam1 > 0.f ? 1 : 0);                               \
    }

// ---------------- Phase 1: routing (levels 0..3 LDS, 2 blocks/CU) ---------
__global__ __launch_bounds__(ROUTE_THREADS, 8) void route_kernel(
    const float* __restrict__ x,
    const float* __restrict__ w1s,
    float* __restrict__ lams16,     // [B][16], one 64B line per sample
    int* __restrict__ bins,         // [512][BIN_CAP]
    int* __restrict__ cnt,          // [512], pre-zeroed
    int B)
{
    extern __shared__ float w1_lds[];   // 15 rows x 1024 f32 = 60KB

    // Stage levels 0..3 (first 15 rows of w1s, contiguous) once per block.
    {
        f32x4* dst = reinterpret_cast<f32x4*>(w1_lds);
        const f32x4* src = reinterpret_cast<const f32x4*>(w1s);
        for (int i = threadIdx.x; i < N_STAGE * 256; i += ROUTE_THREADS)
            dst[i] = src[i];
    }
    __syncthreads();

    const int lane = threadIdx.x & 63;
    const int wslot = blockIdx.x * (ROUTE_THREADS / 64) + (threadIdx.x >> 6);
    const int wstride = gridDim.x * (ROUTE_THREADS / 64);
    const int npairs = B >> 1;
    const int sel = lane & 15;

    for (int pr = wslot; pr < npairs; pr += wstride) {
        const int b0 = pr * 2, b1 = b0 + 1;

        const f32x4* xa = reinterpret_cast<const f32x4*>(x + (size_t)b0 * N_IN);
        const f32x4* xb = reinterpret_cast<const f32x4*>(x + (size_t)b1 * N_IN);
        f32x4 xv0[4], xv1[4];
        #pragma unroll
        for (int c = 0; c < 4; ++c) {
            xv0[c] = __builtin_nontemporal_load(&xa[c * 64 + lane]);
            xv1[c] = __builtin_nontemporal_load(&xb[c * 64 + lane]);
        }

        float myl = 0.f;
        int n0 = 0, n1 = 0;

        // Levels 0..3: rows from LDS.
        #pragma unroll
        for (int d = 0; d < 4; ++d) {
            const f32x4* wa = reinterpret_cast<const f32x4*>(w1_lds + n0 * N_IN);
            const f32x4* wb = reinterpret_cast<const f32x4*>(w1_lds + n1 * N_IN);
            ROUTE_LEVEL_BODY(d, wa, wb)
        }
        // Levels 4..9: rows from global (level 4's 64KB is L1/L2-hot).
        #pragma unroll
        for (int d = 4; d < FFF_DEPTH; ++d) {
            const f32x4* wa = reinterpret_cast<const f32x4*>(w1s + (size_t)n0 * N_IN);
            const f32x4* wb = reinterpret_cast<const f32x4*>(w1s + (size_t)n1 * N_IN);
            ROUTE_LEVEL_BODY(d, wa, wb)
        }

        // One coalesced 128B store covers both samples' lam lines.
        if (lane < 32) lams16[(size_t)b0 * 16 + lane] = (sel < FFF_DEPTH) ? myl : 0.f;

        // Direct bin append (leaf = depth-9 node = parent of final index).
        if (lane == 0) {
            int l0 = ((n0 - 1) >> 1) - LEAF_BASE;
            int p = atomicAdd(&cnt[l0], 1);
            if (p < BIN_CAP) bins[l0 * BIN_CAP + p] = b0;
        }
        if (lane == 1) {
            int l1 = ((n1 - 1) >> 1) - LEAF_BASE;
            int p = atomicAdd(&cnt[l1], 1);
            if (p < BIN_CAP) bins[l1 * BIN_CAP + p] = b1;
        }
    }
}

// ---------------- cnt zeroing (replaces hipMemsetAsync) ----------------
__global__ void zero_cnt_kernel(int* __restrict__ cnt) {
    cnt[threadIdx.x] = 0;
}

// ---------------- Phase 2: y accumulation (byte-identical to R13) ---------
__global__ __launch_bounds__(256, 4) void accum_kernel(
    const float* __restrict__ w2s,
    const float* __restrict__ lams16,
    const int* __restrict__ bins,
    const int* __restrict__ cnt,
    float* __restrict__ y)
{
    __shared__ float lds[FFF_DEPTH * N_OUT];   // 40KB: this leaf-path's w2 rows
    const int leaf = blockIdx.x >> 3;          // 8 blocks per leaf
    const int part = blockIdx.x & 7;

    int nodes[FFF_DEPTH];
    int n = LEAF_BASE + leaf;
    #pragma unroll
    for (int d = FFF_DEPTH - 1; d >= 0; --d) { nodes[d] = n; n = (n - 1) >> 1; }

    const int tid = threadIdx.x;
    f32x4* lds4 = reinterpret_cast<f32x4*>(lds);
    #pragma unroll
    for (int d = 0; d < FFF_DEPTH; ++d) {
        const f32x4* src = reinterpret_cast<const f32x4*>(w2s + (size_t)nodes[d] * N_OUT);
        lds4[d * 256 + tid] = src[tid];        // 256 thr x float4 = one 4KB row
    }
    __syncthreads();

    int nsamp = cnt[leaf];
    if (nsamp > BIN_CAP) nsamp = BIN_CAP;      // safety (never expected)
    const int nq = (nsamp + BLOCKS_PER_LEAF - 1) / BLOCKS_PER_LEAF;
    const int rs = part * nq;
    int re = rs + nq;
    if (re > nsamp) re = nsamp;

    const int lane = tid & 63, wv = tid >> 6;
    const int* mybin = bins + leaf * BIN_CAP;

    int p = rs + wv;

    // Main loop: 2 samples/iter; each LDS w-row read feeds both accumulators.
    for (; p + 4 < re; p += 8) {
        const int b0 = __builtin_amdgcn_readfirstlane(mybin[p]);
        const int b1 = __builtin_amdgcn_readfirstlane(mybin[p + 4]);
        const float lv0 = lams16[(size_t)b0 * 16 + (lane & 15)];
        const float lv1 = lams16[(size_t)b1 * 16 + (lane & 15)];

        f32x4 a0[4], a1[4];
        #pragma unroll
        for (int c = 0; c < 4; ++c) { a0[c] = (f32x4)0.f; a1[c] = (f32x4)0.f; }
        #pragma unroll
        for (int d = 0; d < FFF_DEPTH; ++d) {      // d-ascending, same as ref
            const float s0 = __builtin_bit_cast(float,
                __builtin_amdgcn_readlane(__builtin_bit_cast(int, lv0), d));
            const float s1 = __builtin_bit_cast(float,
                __builtin_amdgcn_readlane(__builtin_bit_cast(int, lv1), d));
            #pragma unroll
            for (int c = 0; c < 4; ++c) {
                const f32x4 w = lds4[d * 256 + c * 64 + lane];
                a0[c] += s0 * w;
                a1[c] += s1 * w;
            }
        }
        f32x4* y0 = reinterpret_cast<f32x4*>(y + (size_t)b0 * N_OUT);
        f32x4* y1 = reinterpret_cast<f32x4*>(y + (size_t)b1 * N_OUT);
        #pragma unroll
        for (int c = 0; c < 4; ++c) {
            store_stream(a0[c], &y0[c * 64 + lane]);
            store_stream(a1[c], &y1[c * 64 + lane]);
        }
    }

    // Tail: one sample at a time.
    for (; p < re; p += 4) {
        const int b = __builtin_amdgcn_readfirstlane(mybin[p]);
        const float lv = lams16[(size_t)b * 16 + (lane & 15)];
        f32x4 acc[4];
        #pragma unroll
        for (int c = 0; c < 4; ++c) acc[c] = (f32x4)0.f;
        #pragma unroll
        for (int d = 0; d < FFF_DEPTH; ++d) {
            const float s = __builtin_bit_cast(float,
                __builtin_amdgcn_readlane(__builtin_bit_cast(int, lv), d));
            #pragma unroll
            for (int c = 0; c < 4; ++c) acc[c] += s * lds4[d * 256 + c * 64 + lane];
        }
        f32x4* y4 = reinterpret_cast<f32x4*>(y + (size_t)b * N_OUT);
        #pragma unroll
        for (int c = 0; c < 4; ++c) store_stream(acc[c], &y4[c * 64 + lane]);
    }
}

// ---------------- Fallback (round-3 proven kernel) ----------------
__global__ __launch_bounds__(256, 4) void fff_mono_kernel(
    const float* __restrict__ x, const float* __restrict__ w1s,
    const float* __restrict__ w2s, float* __restrict__ y, int B)
{
    const int lane = threadIdx.x & 63;
    const int b = blockIdx.x * 4 + (threadIdx.x >> 6);
    if (b >= B) return;
    const f32x4* x4 = reinterpret_cast<const f32x4*>(x + (size_t)b * N_IN);
    f32x4 xv[4], acc[4];
    #pragma unroll
    for (int c = 0; c < 4; ++c) { xv[c] = __builtin_nontemporal_load(&x4[c*64+lane]); acc[c] = (f32x4)0.f; }
    int node = 0;
    #pragma unroll
    for (int d = 0; d < FFF_DEPTH; ++d) {
        const f32x4* w1 = reinterpret_cast<const f32x4*>(w1s + (size_t)node * N_IN);
        const f32x4* w2 = reinterpret_cast<const f32x4*>(w2s + (size_t)node * N_OUT);
        f32x4 w[4], v[4];
        #pragma unroll
        for (int c = 0; c < 4; ++c) { w[c] = w1[c*64+lane]; v[c] = w2[c*64+lane]; }
        float p0=0,p1=0,p2=0,p3=0;
        #pragma unroll
        for (int c = 0; c < 4; ++c) {
            p0 += xv[c][0]*w[c][0]; p1 += xv[c][1]*w[c][1];
            p2 += xv[c][2]*w[c][2]; p3 += xv[c][3]*w[c][3];
        }
        float lam = wave_sum((p0+p1)+(p2+p3));
        #pragma unroll
        for (int c = 0; c < 4; ++c) acc[c] += lam * v[c];
        node = node * 2 + 1 + (lam > 0.f ? 1 : 0);
    }
    f32x4* y4 = reinterpret_cast<f32x4*>(y + (size_t)b * N_OUT);
    #pragma unroll
    for (int c = 0; c < 4; ++c) store_stream(acc[c], &y4[c*64+lane]);
}

extern "C" void kernel_launch(void* const* d_in, const int* in_sizes, int n_in,
                              void* d_out, int out_size, void* d_ws, size_t ws_size,
                              hipStream_t stream) {
    const float* x   = (const float*)d_in[0];
    const float* w1s = (const float*)d_in[1];
    const float* w2s = (const float*)d_in[2];
    float* y = (float*)d_out;
    const int B = in_sizes[0] / N_IN;   // 65536

    float* lams16 = (float*)d_ws;
    int*   bins   = (int*)(lams16 + (size_t)B * 16);
    int*   cnt    = bins + (size_t)N_LEAF * BIN_CAP;
    const size_t need = ((size_t)B * 16 + (size_t)N_LEAF * BIN_CAP + N_LEAF) * 4;

    if (ws_size < need) {   // fallback: monolithic proven path
        fff_mono_kernel<<<(B + 3) / 4, 256, 0, stream>>>(x, w1s, w2s, y, B);
        return;
    }

    zero_cnt_kernel<<<1, N_LEAF, 0, stream>>>(cnt);
    route_kernel<<<ROUTE_BLOCKS, ROUTE_THREADS, N_STAGE * N_IN * sizeof(float), stream>>>(
        x, w1s, lams16, bins, cnt, B);
    accum_kernel<<<BLOCKS_PER_LEAF * N_LEAF, 256, 0, stream>>>(w2s, lams16, bins, cnt, y);
}

// Round 17
// 178.996 us; speedup vs baseline: 1.4479x; 1.4479x over previous
//
#include <hip/hip_runtime.h>

// FFF tree-routed feedforward: B=65536, nIn=nOut=1024, DEPTH=10, n_nodes=1023.
//
// Round-17 (route: fix R16's spill, actually test the occupancy thesis):
//  R16 post-mortem: dynamic LDS hid the occupancy cap from the allocator ->
//  launch_bounds(1024,8) squeezed VGPR to 32 -> 180MB scratch spill (WRITE
//  counter) -> 211us. Two fixes applied together (they are one constraint):
//   (a) STATIC __shared__ 60KB so the compiler sees the 2-block/CU LDS cap
//       and allocates up to 64 VGPR instead of 32.
//   (b) ONE sample per wave (live set ~45 regs, fits 64 without spill);
//       the lost 2-sample ILP is replaced by 2x wave TLP (32 vs 16 waves/CU),
//       the right currency for a latency-bound gather chain.
//  Levels 0..3 from LDS; levels 4..9 from global (level-4's 64KB is L2-hot;
//  R16 confirmed this substitution itself is cheap). Bitwise-identical lams.
//  - accum_kernel: byte-identical to R13 (8 blocks/leaf).
//  - Banked: sc0 sc1 nt streaming y-stores (R7); leaf binning + LDS w2 stage
//    (R5-R7); 8 blocks/leaf (R13). Rejected: 4-sample accum combo (R9/R10),
//    x-prefetch (R11), speculation (R14), dynamic-LDS launch-bounds (R16).

#define FFF_DEPTH 10
#define N_IN 1024
#define N_OUT 1024
#define N_LEAF 512
#define LEAF_BASE 511
#define BIN_CAP 512
#define N_STAGE 15            // nodes in levels 0..3 (60KB static LDS)
#define ROUTE_THREADS 1024
#define ROUTE_BLOCKS 512      // 2 blocks/CU
#define BLOCKS_PER_LEAF 8

typedef float f32x4 __attribute__((ext_vector_type(4)));

template<int CTRL, int ROW_MASK>
__device__ __forceinline__ float dpp_add(float v) {
    int sh = __builtin_amdgcn_update_dpp(0, __builtin_bit_cast(int, v),
                                         CTRL, ROW_MASK, 0xf, true);
    return v + __builtin_bit_cast(float, sh);
}

// Full 64-lane sum, result broadcast via readlane(63) (wave-uniform).
__device__ __forceinline__ float wave_sum(float p) {
    p = dpp_add<0x111, 0xf>(p);
    p = dpp_add<0x112, 0xf>(p);
    p = dpp_add<0x114, 0xf>(p);
    p = dpp_add<0x118, 0xf>(p);
    p = dpp_add<0x142, 0xa>(p);
    p = dpp_add<0x143, 0xc>(p);
    return __builtin_bit_cast(float,
        __builtin_amdgcn_readlane(__builtin_bit_cast(int, p), 63));
}

// System-scope streaming store: bypasses L2 AND MALL allocate, so the store
// does not trigger a line fetch from HBM (R7-verified: killed ~360MB phantom).
__device__ __forceinline__ void store_stream(f32x4 v, f32x4* addr) {
    asm volatile("global_store_dwordx4 %0, %1, off sc0 sc1 nt"
                 :: "v"(addr), "v"(v) : "memory");
}

// ---------------- Phase 1: routing (1 sample/wave, 2 blocks/CU) -----------
__global__ __launch_bounds__(ROUTE_THREADS, 8) void route_kernel(
    const float* __restrict__ x,
    const float* __restrict__ w1s,
    float* __restrict__ lams16,     // [B][16], one 64B line per sample
    int* __restrict__ bins,         // [512][BIN_CAP]
    int* __restrict__ cnt,          // [512], pre-zeroed
    int B)
{
    __shared__ float w1_lds[N_STAGE * N_IN];   // STATIC 60KB: allocator sees
                                               // the 2-block/CU cap -> VGPR 64
    // Stage levels 0..3 (first 15 rows of w1s, contiguous) once per block.
    {
        f32x4* dst = reinterpret_cast<f32x4*>(w1_lds);
        const f32x4* src = reinterpret_cast<const f32x4*>(w1s);
        for (int i = threadIdx.x; i < N_STAGE * 256; i += ROUTE_THREADS)
            dst[i] = src[i];
    }
    __syncthreads();

    const int lane = threadIdx.x & 63;
    const int wslot = blockIdx.x * (ROUTE_THREADS / 64) + (threadIdx.x >> 6);
    const int wstride = gridDim.x * (ROUTE_THREADS / 64);
    const int sel = lane & 15;

    for (int b = wslot; b < B; b += wstride) {
        const f32x4* x4 = reinterpret_cast<const f32x4*>(x + (size_t)b * N_IN);
        f32x4 xv[4];
        #pragma unroll
        for (int c = 0; c < 4; ++c)
            xv[c] = __builtin_nontemporal_load(&x4[c * 64 + lane]);

        float myl = 0.f;
        int node = 0;

        // Levels 0..3: rows from LDS. Same chunk/chain op order as all prior
        // rounds -> bitwise-identical lams.
        #pragma unroll
        for (int d = 0; d < 4; ++d) {
            const f32x4* w = reinterpret_cast<const f32x4*>(w1_lds + node * N_IN);
            float p0 = 0.f, p1 = 0.f, p2 = 0.f, p3 = 0.f;
            #pragma unroll
            for (int c = 0; c < 4; ++c) {
                const f32x4 wv = w[c * 64 + lane];
                p0 += xv[c][0] * wv[0];
                p1 += xv[c][1] * wv[1];
                p2 += xv[c][2] * wv[2];
                p3 += xv[c][3] * wv[3];
            }
            const float lam = wave_sum((p0 + p1) + (p2 + p3));
            myl = (sel == d) ? lam : myl;
            node = node * 2 + 1 + (lam > 0.f ? 1 : 0);
        }
        // Levels 4..9: rows from global (level 4's 64KB is L1/L2-hot).
        #pragma unroll
        for (int d = 4; d < FFF_DEPTH; ++d) {
            const f32x4* w = reinterpret_cast<const f32x4*>(w1s + (size_t)node * N_IN);
            float p0 = 0.f, p1 = 0.f, p2 = 0.f, p3 = 0.f;
            #pragma unroll
            for (int c = 0; c < 4; ++c) {
                const f32x4 wv = w[c * 64 + lane];
                p0 += xv[c][0] * wv[0];
                p1 += xv[c][1] * wv[1];
                p2 += xv[c][2] * wv[2];
                p3 += xv[c][3] * wv[3];
            }
            const float lam = wave_sum((p0 + p1) + (p2 + p3));
            myl = (sel == d) ? lam : myl;
            node = node * 2 + 1 + (lam > 0.f ? 1 : 0);
        }

        // One coalesced 64B store: this sample's lam line.
        if (lane < 16) lams16[(size_t)b * 16 + lane] = (lane < FFF_DEPTH) ? myl : 0.f;

        // Direct bin append (leaf = depth-9 node = parent of final index).
        if (lane == 0) {
            int l = ((node - 1) >> 1) - LEAF_BASE;
            int p = atomicAdd(&cnt[l], 1);
            if (p < BIN_CAP) bins[l * BIN_CAP + p] = b;
        }
    }
}

// ---------------- cnt zeroing (replaces hipMemsetAsync) ----------------
__global__ void zero_cnt_kernel(int* __restrict__ cnt) {
    cnt[threadIdx.x] = 0;
}

// ---------------- Phase 2: y accumulation (byte-identical to R13) ---------
__global__ __launch_bounds__(256, 4) void accum_kernel(
    const float* __restrict__ w2s,
    const float* __restrict__ lams16,
    const int* __restrict__ bins,
    const int* __restrict__ cnt,
    float* __restrict__ y)
{
    __shared__ float lds[FFF_DEPTH * N_OUT];   // 40KB: this leaf-path's w2 rows
    const int leaf = blockIdx.x >> 3;          // 8 blocks per leaf
    const int part = blockIdx.x & 7;

    int nodes[FFF_DEPTH];
    int n = LEAF_BASE + leaf;
    #pragma unroll
    for (int d = FFF_DEPTH - 1; d >= 0; --d) { nodes[d] = n; n = (n - 1) >> 1; }

    const int tid = threadIdx.x;
    f32x4* lds4 = reinterpret_cast<f32x4*>(lds);
    #pragma unroll
    for (int d = 0; d < FFF_DEPTH; ++d) {
        const f32x4* src = reinterpret_cast<const f32x4*>(w2s + (size_t)nodes[d] * N_OUT);
        lds4[d * 256 + tid] = src[tid];        // 256 thr x float4 = one 4KB row
    }
    __syncthreads();

    int nsamp = cnt[leaf];
    if (nsamp > BIN_CAP) nsamp = BIN_CAP;      // safety (never expected)
    const int nq = (nsamp + BLOCKS_PER_LEAF - 1) / BLOCKS_PER_LEAF;
    const int rs = part * nq;
    int re = rs + nq;
    if (re > nsamp) re = nsamp;

    const int lane = tid & 63, wv = tid >> 6;
    const int* mybin = bins + leaf * BIN_CAP;

    int p = rs + wv;

    // Main loop: 2 samples/iter; each LDS w-row read feeds both accumulators.
    for (; p + 4 < re; p += 8) {
        const int b0 = __builtin_amdgcn_readfirstlane(mybin[p]);
        const int b1 = __builtin_amdgcn_readfirstlane(mybin[p + 4]);
        const float lv0 = lams16[(size_t)b0 * 16 + (lane & 15)];
        const float lv1 = lams16[(size_t)b1 * 16 + (lane & 15)];

        f32x4 a0[4], a1[4];
        #pragma unroll
        for (int c = 0; c < 4; ++c) { a0[c] = (f32x4)0.f; a1[c] = (f32x4)0.f; }
        #pragma unroll
        for (int d = 0; d < FFF_DEPTH; ++d) {      // d-ascending, same as ref
            const float s0 = __builtin_bit_cast(float,
                __builtin_amdgcn_readlane(__builtin_bit_cast(int, lv0), d));
            const float s1 = __builtin_bit_cast(float,
                __builtin_amdgcn_readlane(__builtin_bit_cast(int, lv1), d));
            #pragma unroll
            for (int c = 0; c < 4; ++c) {
                const f32x4 w = lds4[d * 256 + c * 64 + lane];
                a0[c] += s0 * w;
                a1[c] += s1 * w;
            }
        }
        f32x4* y0 = reinterpret_cast<f32x4*>(y + (size_t)b0 * N_OUT);
        f32x4* y1 = reinterpret_cast<f32x4*>(y + (size_t)b1 * N_OUT);
        #pragma unroll
        for (int c = 0; c < 4; ++c) {
            store_stream(a0[c], &y0[c * 64 + lane]);
            store_stream(a1[c], &y1[c * 64 + lane]);
        }
    }

    // Tail: one sample at a time.
    for (; p < re; p += 4) {
        const int b = __builtin_amdgcn_readfirstlane(mybin[p]);
        const float lv = lams16[(size_t)b * 16 + (lane & 15)];
        f32x4 acc[4];
        #pragma unroll
        for (int c = 0; c < 4; ++c) acc[c] = (f32x4)0.f;
        #pragma unroll
        for (int d = 0; d < FFF_DEPTH; ++d) {
            const float s = __builtin_bit_cast(float,
                __builtin_amdgcn_readlane(__builtin_bit_cast(int, lv), d));
            #pragma unroll
            for (int c = 0; c < 4; ++c) acc[c] += s * lds4[d * 256 + c * 64 + lane];
        }
        f32x4* y4 = reinterpret_cast<f32x4*>(y + (size_t)b * N_OUT);
        #pragma unroll
        for (int c = 0; c < 4; ++c) store_stream(acc[c], &y4[c * 64 + lane]);
    }
}

// ---------------- Fallback (round-3 proven kernel) ----------------
__global__ __launch_bounds__(256, 4) void fff_mono_kernel(
    const float* __restrict__ x, const float* __restrict__ w1s,
    const float* __restrict__ w2s, float* __restrict__ y, int B)
{
    const int lane = threadIdx.x & 63;
    const int b = blockIdx.x * 4 + (threadIdx.x >> 6);
    if (b >= B) return;
    const f32x4* x4 = reinterpret_cast<const f32x4*>(x + (size_t)b * N_IN);
    f32x4 xv[4], acc[4];
    #pragma unroll
    for (int c = 0; c < 4; ++c) { xv[c] = __builtin_nontemporal_load(&x4[c*64+lane]); acc[c] = (f32x4)0.f; }
    int node = 0;
    #pragma unroll
    for (int d = 0; d < FFF_DEPTH; ++d) {
        const f32x4* w1 = reinterpret_cast<const f32x4*>(w1s + (size_t)node * N_IN);
        const f32x4* w2 = reinterpret_cast<const f32x4*>(w2s + (size_t)node * N_OUT);
        f32x4 w[4], v[4];
        #pragma unroll
        for (int c = 0; c < 4; ++c) { w[c] = w1[c*64+lane]; v[c] = w2[c*64+lane]; }
        float p0=0,p1=0,p2=0,p3=0;
        #pragma unroll
        for (int c = 0; c < 4; ++c) {
            p0 += xv[c][0]*w[c][0]; p1 += xv[c][1]*w[c][1];
            p2 += xv[c][2]*w[c][2]; p3 += xv[c][3]*w[c][3];
        }
        float lam = wave_sum((p0+p1)+(p2+p3));
        #pragma unroll
        for (int c = 0; c < 4; ++c) acc[c] += lam * v[c];
        node = node * 2 + 1 + (lam > 0.f ? 1 : 0);
    }
    f32x4* y4 = reinterpret_cast<f32x4*>(y + (size_t)b * N_OUT);
    #pragma unroll
    for (int c = 0; c < 4; ++c) store_stream(acc[c], &y4[c*64+lane]);
}

extern "C" void kernel_launch(void* const* d_in, const int* in_sizes, int n_in,
                              void* d_out, int out_size, void* d_ws, size_t ws_size,
                              hipStream_t stream) {
    const float* x   = (const float*)d_in[0];
    const float* w1s = (const float*)d_in[1];
    const float* w2s = (const float*)d_in[2];
    float* y = (float*)d_out;
    const int B = in_sizes[0] / N_IN;   // 65536

    float* lams16 = (float*)d_ws;
    int*   bins   = (int*)(lams16 + (size_t)B * 16);
    int*   cnt    = bins + (size_t)N_LEAF * BIN_CAP;
    const size_t need = ((size_t)B * 16 + (size_t)N_LEAF * BIN_CAP + N_LEAF) * 4;

    if (ws_size < need) {   // fallback: monolithic proven path
        fff_mono_kernel<<<(B + 3) / 4, 256, 0, stream>>>(x, w1s, w2s, y, B);
        return;
    }

    zero_cnt_kernel<<<1, N_LEAF, 0, stream>>>(cnt);
    route_kernel<<<ROUTE_BLOCKS, ROUTE_THREADS, 0, stream>>>(
        x, w1s, lams16, bins, cnt, B);
    accum_kernel<<<BLOCKS_PER_LEAF * N_LEAF, 256, 0, stream>>>(w2s, lams16, bins, cnt, y);
}

// Round 18
// 165.816 us; speedup vs baseline: 1.5630x; 1.0795x over previous
//
#include <hip/hip_runtime.h>

// FFF tree-routed feedforward: B=65536, nIn=nOut=1024, DEPTH=10, n_nodes=1023.
//
// Round-18: FINAL — pure revert to the R13/R15 configuration (best measured:
// 164.6 / 167.4 us, reproduced twice).
//
// Route lever ledger (all tested, all regressed except the banked set):
//   R8  LDS stage levels 0..4 + 2-sample/wave @ 1 blk/CU   -> BEST (~100us)
//   R11 x-prefetch pipeline        -> +6us  (VGPR pressure @ 1 blk/CU)
//   R14 speculative 2x dots        -> +54us (VALU/occupancy-bound)
//   R16 2 blk/CU via dynamic LDS   -> +111us (allocator spill, 32 VGPR)
//   R17 2 blk/CU static LDS 1-samp -> +19us (per-wave ILP loss > TLP gain)
// => route is at its dependent-gather vector-L1 wall.
// Accum: 8 blk/leaf load-balance curve flat (R12 +6, R13 +3.8, further ~0);
// ~15us above its 262MB streaming-store floor. Total floor ~155-165us for
// this decomposition.
//
// Banked techniques: sc0 sc1 nt streaming y-stores (R7: kills MALL
// write-allocate phantom fetch, -110us); leaf binning + per-leaf LDS w2
// stage (R5-R7); lam-line 64B layout + readlane broadcast (R7); blocks/leaf
// load balance (R12/R13). Rejected: 4-sample accum combo (silently corrupts,
// R9/R10 - mechanism unresolved); all route levers above.

#define FFF_DEPTH 10
#define N_IN 1024
#define N_OUT 1024
#define N_LEAF 512
#define LEAF_BASE 511
#define BIN_CAP 512
#define N_STAGE 31            // nodes in levels 0..4
#define ROUTE_THREADS 1024
#define ROUTE_BLOCKS 256
#define BLOCKS_PER_LEAF 8

typedef float f32x4 __attribute__((ext_vector_type(4)));

template<int CTRL, int ROW_MASK>
__device__ __forceinline__ float dpp_add(float v) {
    int sh = __builtin_amdgcn_update_dpp(0, __builtin_bit_cast(int, v),
                                         CTRL, ROW_MASK, 0xf, true);
    return v + __builtin_bit_cast(float, sh);
}

// Full 64-lane sum, result broadcast via readlane(63) (wave-uniform).
__device__ __forceinline__ float wave_sum(float p) {
    p = dpp_add<0x111, 0xf>(p);
    p = dpp_add<0x112, 0xf>(p);
    p = dpp_add<0x114, 0xf>(p);
    p = dpp_add<0x118, 0xf>(p);
    p = dpp_add<0x142, 0xa>(p);
    p = dpp_add<0x143, 0xc>(p);
    return __builtin_bit_cast(float,
        __builtin_amdgcn_readlane(__builtin_bit_cast(int, p), 63));
}

// System-scope streaming store: bypasses L2 AND MALL allocate, so the store
// does not trigger a line fetch from HBM (R7-verified: killed ~360MB phantom).
__device__ __forceinline__ void store_stream(f32x4 v, f32x4* addr) {
    asm volatile("global_store_dwordx4 %0, %1, off sc0 sc1 nt"
                 :: "v"(addr), "v"(v) : "memory");
}

// One routing level for both of the wave's samples. Math identical across
// LDS/global sources (same op order) -> bitwise-stable lams.
#define ROUTE_LEVEL_BODY(dd, wa, wb)                                          \
    {                                                                         \
        f32x4 w0[4], w1v[4];                                                  \
        _Pragma("unroll")                                                     \
        for (int c = 0; c < 4; ++c) {                                         \
            w0[c] = (wa)[c * 64 + lane];                                      \
            w1v[c] = (wb)[c * 64 + lane];                                     \
        }                                                                     \
        float p0 = 0.f, p1 = 0.f, p2 = 0.f, p3 = 0.f;                         \
        float q0 = 0.f, q1 = 0.f, q2 = 0.f, q3 = 0.f;                         \
        _Pragma("unroll")                                                     \
        for (int c = 0; c < 4; ++c) {                                         \
            p0 += xv0[c][0] * w0[c][0];  q0 += xv1[c][0] * w1v[c][0];         \
            p1 += xv0[c][1] * w0[c][1];  q1 += xv1[c][1] * w1v[c][1];         \
            p2 += xv0[c][2] * w0[c][2];  q2 += xv1[c][2] * w1v[c][2];         \
            p3 += xv0[c][3] * w0[c][3];  q3 += xv1[c][3] * w1v[c][3];         \
        }                                                                     \
        const float lam0 = wave_sum((p0 + p1) + (p2 + p3));                   \
        const float lam1 = wave_sum((q0 + q1) + (q2 + q3));                   \
        const float pick = (lane < 16) ? lam0 : lam1;                         \
        myl = (sel == (dd)) ? pick : myl;                                     \
        n0 = n0 * 2 + 1 + (lam0 > 0.f ? 1 : 0);                               \
        n1 = n1 * 2 + 1 + (lam1 > 0.f ? 1 : 0);                               \
    }

// ---------------- Phase 1: routing (byte-identical to R8/R12/R13) ---------
__global__ __launch_bounds__(ROUTE_THREADS, 4) void route_kernel(
    const float* __restrict__ x,
    const float* __restrict__ w1s,
    float* __restrict__ lams16,     // [B][16], one 64B line per sample
    int* __restrict__ bins,         // [512][BIN_CAP]
    int* __restrict__ cnt,          // [512], pre-zeroed
    int B)
{
    extern __shared__ float w1_lds[];   // 31 rows x 1024 f32 = 124KB

    // Stage levels 0..4 (first 31 rows of w1s, contiguous) once per block.
    {
        f32x4* dst = reinterpret_cast<f32x4*>(w1_lds);
        const f32x4* src = reinterpret_cast<const f32x4*>(w1s);
        for (int i = threadIdx.x; i < N_STAGE * 256; i += ROUTE_THREADS)
            dst[i] = src[i];
    }
    __syncthreads();

    const int lane = threadIdx.x & 63;
    const int wslot = blockIdx.x * (ROUTE_THREADS / 64) + (threadIdx.x >> 6);
    const int wstride = gridDim.x * (ROUTE_THREADS / 64);
    const int npairs = B >> 1;
    const int sel = lane & 15;

    for (int pr = wslot; pr < npairs; pr += wstride) {
        const int b0 = pr * 2, b1 = b0 + 1;

        const f32x4* xa = reinterpret_cast<const f32x4*>(x + (size_t)b0 * N_IN);
        const f32x4* xb = reinterpret_cast<const f32x4*>(x + (size_t)b1 * N_IN);
        f32x4 xv0[4], xv1[4];
        #pragma unroll
        for (int c = 0; c < 4; ++c) {
            xv0[c] = __builtin_nontemporal_load(&xa[c * 64 + lane]);
            xv1[c] = __builtin_nontemporal_load(&xb[c * 64 + lane]);
        }

        float myl = 0.f;
        int n0 = 0, n1 = 0;

        // Levels 0..4: rows from LDS.
        #pragma unroll
        for (int d = 0; d < 5; ++d) {
            const f32x4* wa = reinterpret_cast<const f32x4*>(w1_lds + n0 * N_IN);
            const f32x4* wb = reinterpret_cast<const f32x4*>(w1_lds + n1 * N_IN);
            ROUTE_LEVEL_BODY(d, wa, wb)
        }
        // Levels 5..9: rows from global (L1/L2).
        #pragma unroll
        for (int d = 5; d < FFF_DEPTH; ++d) {
            const f32x4* wa = reinterpret_cast<const f32x4*>(w1s + (size_t)n0 * N_IN);
            const f32x4* wb = reinterpret_cast<const f32x4*>(w1s + (size_t)n1 * N_IN);
            ROUTE_LEVEL_BODY(d, wa, wb)
        }

        // One coalesced 128B store covers both samples' lam lines.
        if (lane < 32) lams16[(size_t)b0 * 16 + lane] = (sel < FFF_DEPTH) ? myl : 0.f;

        // Direct bin append (leaf = depth-9 node = parent of final index).
        if (lane == 0) {
            int l0 = ((n0 - 1) >> 1) - LEAF_BASE;
            int p = atomicAdd(&cnt[l0], 1);
            if (p < BIN_CAP) bins[l0 * BIN_CAP + p] = b0;
        }
        if (lane == 1) {
            int l1 = ((n1 - 1) >> 1) - LEAF_BASE;
            int p = atomicAdd(&cnt[l1], 1);
            if (p < BIN_CAP) bins[l1 * BIN_CAP + p] = b1;
        }
    }
}

// ---------------- cnt zeroing (replaces hipMemsetAsync) ----------------
__global__ void zero_cnt_kernel(int* __restrict__ cnt) {
    cnt[threadIdx.x] = 0;
}

// ---------------- Phase 2: y accumulation (byte-identical to R13) ---------
__global__ __launch_bounds__(256, 4) void accum_kernel(
    const float* __restrict__ w2s,
    const float* __restrict__ lams16,
    const int* __restrict__ bins,
    const int* __restrict__ cnt,
    float* __restrict__ y)
{
    __shared__ float lds[FFF_DEPTH * N_OUT];   // 40KB: this leaf-path's w2 rows
    const int leaf = blockIdx.x >> 3;          // 8 blocks per leaf
    const int part = blockIdx.x & 7;

    int nodes[FFF_DEPTH];
    int n = LEAF_BASE + leaf;
    #pragma unroll
    for (int d = FFF_DEPTH - 1; d >= 0; --d) { nodes[d] = n; n = (n - 1) >> 1; }

    const int tid = threadIdx.x;
    f32x4* lds4 = reinterpret_cast<f32x4*>(lds);
    #pragma unroll
    for (int d = 0; d < FFF_DEPTH; ++d) {
        const f32x4* src = reinterpret_cast<const f32x4*>(w2s + (size_t)nodes[d] * N_OUT);
        lds4[d * 256 + tid] = src[tid];        // 256 thr x float4 = one 4KB row
    }
    __syncthreads();

    int nsamp = cnt[leaf];
    if (nsamp > BIN_CAP) nsamp = BIN_CAP;      // safety (never expected)
    const int nq = (nsamp + BLOCKS_PER_LEAF - 1) / BLOCKS_PER_LEAF;
    const int rs = part * nq;
    int re = rs + nq;
    if (re > nsamp) re = nsamp;

    const int lane = tid & 63, wv = tid >> 6;
    const int* mybin = bins + leaf * BIN_CAP;

    int p = rs + wv;

    // Main loop: 2 samples/iter; each LDS w-row read feeds both accumulators.
    for (; p + 4 < re; p += 8) {
        const int b0 = __builtin_amdgcn_readfirstlane(mybin[p]);
        const int b1 = __builtin_amdgcn_readfirstlane(mybin[p + 4]);
        const float lv0 = lams16[(size_t)b0 * 16 + (lane & 15)];
        const float lv1 = lams16[(size_t)b1 * 16 + (lane & 15)];

        f32x4 a0[4], a1[4];
        #pragma unroll
        for (int c = 0; c < 4; ++c) { a0[c] = (f32x4)0.f; a1[c] = (f32x4)0.f; }
        #pragma unroll
        for (int d = 0; d < FFF_DEPTH; ++d) {      // d-ascending, same as ref
            const float s0 = __builtin_bit_cast(float,
                __builtin_amdgcn_readlane(__builtin_bit_cast(int, lv0), d));
            const float s1 = __builtin_bit_cast(float,
                __builtin_amdgcn_readlane(__builtin_bit_cast(int, lv1), d));
            #pragma unroll
            for (int c = 0; c < 4; ++c) {
                const f32x4 w = lds4[d * 256 + c * 64 + lane];
                a0[c] += s0 * w;
                a1[c] += s1 * w;
            }
        }
        f32x4* y0 = reinterpret_cast<f32x4*>(y + (size_t)b0 * N_OUT);
        f32x4* y1 = reinterpret_cast<f32x4*>(y + (size_t)b1 * N_OUT);
        #pragma unroll
        for (int c = 0; c < 4; ++c) {
            store_stream(a0[c], &y0[c * 64 + lane]);
            store_stream(a1[c], &y1[c * 64 + lane]);
        }
    }

    // Tail: one sample at a time.
    for (; p < re; p += 4) {
        const int b = __builtin_amdgcn_readfirstlane(mybin[p]);
        const float lv = lams16[(size_t)b * 16 + (lane & 15)];
        f32x4 acc[4];
        #pragma unroll
        for (int c = 0; c < 4; ++c) acc[c] = (f32x4)0.f;
        #pragma unroll
        for (int d = 0; d < FFF_DEPTH; ++d) {
            const float s = __builtin_bit_cast(float,
                __builtin_amdgcn_readlane(__builtin_bit_cast(int, lv), d));
            #pragma unroll
            for (int c = 0; c < 4; ++c) acc[c] += s * lds4[d * 256 + c * 64 + lane];
        }
        f32x4* y4 = reinterpret_cast<f32x4*>(y + (size_t)b * N_OUT);
        #pragma unroll
        for (int c = 0; c < 4; ++c) store_stream(acc[c], &y4[c * 64 + lane]);
    }
}

// ---------------- Fallback (round-3 proven kernel) ----------------
__global__ __launch_bounds__(256, 4) void fff_mono_kernel(
    const float* __restrict__ x, const float* __restrict__ w1s,
    const float* __restrict__ w2s, float* __restrict__ y, int B)
{
    const int lane = threadIdx.x & 63;
    const int b = blockIdx.x * 4 + (threadIdx.x >> 6);
    if (b >= B) return;
    const f32x4* x4 = reinterpret_cast<const f32x4*>(x + (size_t)b * N_IN);
    f32x4 xv[4], acc[4];
    #pragma unroll
    for (int c = 0; c < 4; ++c) { xv[c] = __builtin_nontemporal_load(&x4[c*64+lane]); acc[c] = (f32x4)0.f; }
    int node = 0;
    #pragma unroll
    for (int d = 0; d < FFF_DEPTH; ++d) {
        const f32x4* w1 = reinterpret_cast<const f32x4*>(w1s + (size_t)node * N_IN);
        const f32x4* w2 = reinterpret_cast<const f32x4*>(w2s + (size_t)node * N_OUT);
        f32x4 w[4], v[4];
        #pragma unroll
        for (int c = 0; c < 4; ++c) { w[c] = w1[c*64+lane]; v[c] = w2[c*64+lane]; }
        float p0=0,p1=0,p2=0,p3=0;
        #pragma unroll
        for (int c = 0; c < 4; ++c) {
            p0 += xv[c][0]*w[c][0]; p1 += xv[c][1]*w[c][1];
            p2 += xv[c][2]*w[c][2]; p3 += xv[c][3]*w[c][3];
        }
        float lam = wave_sum((p0+p1)+(p2+p3));
        #pragma unroll
        for (int c = 0; c < 4; ++c) acc[c] += lam * v[c];
        node = node * 2 + 1 + (lam > 0.f ? 1 : 0);
    }
    f32x4* y4 = reinterpret_cast<f32x4*>(y + (size_t)b * N_OUT);
    #pragma unroll
    for (int c = 0; c < 4; ++c) store_stream(acc[c], &y4[c*64+lane]);
}

extern "C" void kernel_launch(void* const* d_in, const int* in_sizes, int n_in,
                              void* d_out, int out_size, void* d_ws, size_t ws_size,
                              hipStream_t stream) {
    const float* x   = (const float*)d_in[0];
    const float* w1s = (const float*)d_in[1];
    const float* w2s = (const float*)d_in[2];
    float* y = (float*)d_out;
    const int B = in_sizes[0] / N_IN;   // 65536

    float* lams16 = (float*)d_ws;
    int*   bins   = (int*)(lams16 + (size_t)B * 16);
    int*   cnt    = bins + (size_t)N_LEAF * BIN_CAP;
    const size_t need = ((size_t)B * 16 + (size_t)N_LEAF * BIN_CAP + N_LEAF) * 4;

    if (ws_size < need) {   // fallback: monolithic proven path
        fff_mono_kernel<<<(B + 3) / 4, 256, 0, stream>>>(x, w1s, w2s, y, B);
        return;
    }

    zero_cnt_kernel<<<1, N_LEAF, 0, stream>>>(cnt);
    route_kernel<<<ROUTE_BLOCKS, ROUTE_THREADS, N_STAGE * N_IN * sizeof(float), stream>>>(
        x, w1s, lams16, bins, cnt, B);
    accum_kernel<<<BLOCKS_PER_LEAF * N_LEAF, 256, 0, stream>>>(w2s, lams16, bins, cnt, y);
}